// Round 1
// baseline (1108.923 us; speedup 1.0000x reference)
//
#include <hip/hip_runtime.h>
#include <math.h>

// Problem constants (from reference: latent (2, 8192, 512) fp32, sample 0 only)
#define NPTS 8192
#define DIM 512
#define KNN 5

// Tiling
#define RT 64      // rows per block
#define CT 64      // cols per tile
#define KT 32      // K chunk staged in LDS
#define CSPLIT 4   // column splits (grid = 128 row-tiles * 4 = 512 blocks)
#define COLS_PER_SPLIT (NPTS / CSPLIT)
#define LDA 68     // padded LDS stride (floats): 68*4B = 272B -> 16B aligned rows, bank-spread
#define LDB 68

// Branch-free sorted insert of v into ascending 5-list (static indices only;
// avoids runtime-indexed arrays -> scratch, rule #20)
#define INSERT5(t0, t1, t2, t3, t4, v)            \
  do {                                            \
    float _m0 = fmaxf(t0, v);  t0 = fminf(t0, v); \
    float _m1 = fmaxf(t1, _m0); t1 = fminf(t1, _m0); \
    float _m2 = fmaxf(t2, _m1); t2 = fminf(t2, _m1); \
    float _m3 = fmaxf(t3, _m2); t3 = fminf(t3, _m2); \
    t4 = fminf(t4, _m3);                          \
  } while (0)

// ---------------------------------------------------------------------------
// Kernel 1: per-row sum of squares. One wave (64 lanes) per row.
__global__ __launch_bounds__(256) void k_rowsq(const float* __restrict__ X,
                                               float* __restrict__ sq) {
  int gt = blockIdx.x * 256 + threadIdx.x;
  int row = gt >> 6;
  int lane = gt & 63;
  if (row >= NPTS) return;
  const float* r = X + (size_t)row * DIM;
  float4 a = *(const float4*)(r + lane * 8);
  float4 b = *(const float4*)(r + lane * 8 + 4);
  float s = a.x * a.x + a.y * a.y + a.z * a.z + a.w * a.w
          + b.x * b.x + b.y * b.y + b.z * b.z + b.w * b.w;
#pragma unroll
  for (int o = 32; o > 0; o >>= 1) s += __shfl_down(s, o);
  if (lane == 0) sq[row] = s;
}

// ---------------------------------------------------------------------------
// Kernel 2: fused distance-GEMM + per-row top-5-smallest (per column split).
// Block: 256 threads = 16x16; each thread computes a 4x4 sub-tile of dots.
__global__ __launch_bounds__(256) void k_knn(const float* __restrict__ X,
                                             const float* __restrict__ sq,
                                             float* __restrict__ topout) {
  __shared__ float smem[5120];            // 20 KB: staging (4352) / merge (5120)
  float* as = smem;                       // [KT][LDA]
  float* bs = smem + KT * LDA;            // [KT][LDB]

  const int tid = threadIdx.x;
  const int tx = tid & 15;                // column group
  const int ty = tid >> 4;                // row group
  const int rt = blockIdx.x / CSPLIT;
  const int cs = blockIdx.x % CSPLIT;
  const int r0 = rt * RT;
  const int cbase = cs * COLS_PER_SPLIT;

  float sqr0 = sq[r0 + ty * 4 + 0];
  float sqr1 = sq[r0 + ty * 4 + 1];
  float sqr2 = sq[r0 + ty * 4 + 2];
  float sqr3 = sq[r0 + ty * 4 + 3];

  // per-thread top-5 (ascending) per owned row — all static-indexed
  float t00 = INFINITY, t01 = INFINITY, t02 = INFINITY, t03 = INFINITY, t04 = INFINITY;
  float t10 = INFINITY, t11 = INFINITY, t12 = INFINITY, t13 = INFINITY, t14 = INFINITY;
  float t20 = INFINITY, t21 = INFINITY, t22 = INFINITY, t23 = INFINITY, t24 = INFINITY;
  float t30 = INFINITY, t31 = INFINITY, t32 = INFINITY, t33 = INFINITY, t34 = INFINITY;

  const int arow = tid >> 3;              // 0..31
  const int ak = (tid & 7) * 4;           // 0,4,..,28

  for (int ct = 0; ct < COLS_PER_SPLIT / CT; ++ct) {
    const int c0 = cbase + ct * CT;
    float acc[4][4];
#pragma unroll
    for (int i = 0; i < 4; ++i)
#pragma unroll
      for (int j = 0; j < 4; ++j) acc[i][j] = 0.f;

    for (int k0 = 0; k0 < DIM; k0 += KT) {
      __syncthreads();
#pragma unroll
      for (int h = 0; h < 2; ++h) {
        int rr = arow + h * 32;
        float4 va = *(const float4*)&X[(size_t)(r0 + rr) * DIM + k0 + ak];
        as[(ak + 0) * LDA + rr] = va.x;
        as[(ak + 1) * LDA + rr] = va.y;
        as[(ak + 2) * LDA + rr] = va.z;
        as[(ak + 3) * LDA + rr] = va.w;
        float4 vb = *(const float4*)&X[(size_t)(c0 + rr) * DIM + k0 + ak];
        bs[(ak + 0) * LDB + rr] = vb.x;
        bs[(ak + 1) * LDB + rr] = vb.y;
        bs[(ak + 2) * LDB + rr] = vb.z;
        bs[(ak + 3) * LDB + rr] = vb.w;
      }
      __syncthreads();
#pragma unroll
      for (int k = 0; k < KT; ++k) {
        float4 a = *(const float4*)&as[k * LDA + ty * 4];
        float4 b = *(const float4*)&bs[k * LDB + tx * 4];
        acc[0][0] = fmaf(a.x, b.x, acc[0][0]);
        acc[0][1] = fmaf(a.x, b.y, acc[0][1]);
        acc[0][2] = fmaf(a.x, b.z, acc[0][2]);
        acc[0][3] = fmaf(a.x, b.w, acc[0][3]);
        acc[1][0] = fmaf(a.y, b.x, acc[1][0]);
        acc[1][1] = fmaf(a.y, b.y, acc[1][1]);
        acc[1][2] = fmaf(a.y, b.z, acc[1][2]);
        acc[1][3] = fmaf(a.y, b.w, acc[1][3]);
        acc[2][0] = fmaf(a.z, b.x, acc[2][0]);
        acc[2][1] = fmaf(a.z, b.y, acc[2][1]);
        acc[2][2] = fmaf(a.z, b.z, acc[2][2]);
        acc[2][3] = fmaf(a.z, b.w, acc[2][3]);
        acc[3][0] = fmaf(a.w, b.x, acc[3][0]);
        acc[3][1] = fmaf(a.w, b.y, acc[3][1]);
        acc[3][2] = fmaf(a.w, b.z, acc[3][2]);
        acc[3][3] = fmaf(a.w, b.w, acc[3][3]);
      }
    }

    // fused epilogue: d2 = sq_i + sq_j - 2*dot; branch-free top-5 insert
#pragma unroll
    for (int j = 0; j < 4; ++j) {
      float sqc = sq[c0 + tx * 4 + j];
      float v0 = fmaf(-2.f, acc[0][j], sqr0 + sqc);
      float v1 = fmaf(-2.f, acc[1][j], sqr1 + sqc);
      float v2 = fmaf(-2.f, acc[2][j], sqr2 + sqc);
      float v3 = fmaf(-2.f, acc[3][j], sqr3 + sqc);
      INSERT5(t00, t01, t02, t03, t04, v0);
      INSERT5(t10, t11, t12, t13, t14, v1);
      INSERT5(t20, t21, t22, t23, t24, v2);
      INSERT5(t30, t31, t32, t33, t34, v3);
    }
  }

  // merge the 16 per-thread lists of each row (16 threads share a row group)
  __syncthreads();
  {
    float* m = smem;
    int base0 = (ty * 4 + 0) * 80 + tx * 5;
    int base1 = (ty * 4 + 1) * 80 + tx * 5;
    int base2 = (ty * 4 + 2) * 80 + tx * 5;
    int base3 = (ty * 4 + 3) * 80 + tx * 5;
    m[base0 + 0] = t00; m[base0 + 1] = t01; m[base0 + 2] = t02; m[base0 + 3] = t03; m[base0 + 4] = t04;
    m[base1 + 0] = t10; m[base1 + 1] = t11; m[base1 + 2] = t12; m[base1 + 3] = t13; m[base1 + 4] = t14;
    m[base2 + 0] = t20; m[base2 + 1] = t21; m[base2 + 2] = t22; m[base2 + 3] = t23; m[base2 + 4] = t24;
    m[base3 + 0] = t30; m[base3 + 1] = t31; m[base3 + 2] = t32; m[base3 + 3] = t33; m[base3 + 4] = t34;
  }
  __syncthreads();
  if (tid < RT) {
    float b0 = INFINITY, b1 = INFINITY, b2 = INFINITY, b3 = INFINITY, b4 = INFINITY;
    const float* p = smem + tid * 80;
    for (int q = 0; q < 80; ++q) {
      float v = p[q];
      INSERT5(b0, b1, b2, b3, b4, v);
    }
    float* o = topout + ((size_t)(r0 + tid) * CSPLIT + cs) * KNN;
    o[0] = b0 > 0.f ? sqrtf(b0) : 0.f;
    o[1] = b1 > 0.f ? sqrtf(b1) : 0.f;
    o[2] = b2 > 0.f ? sqrtf(b2) : 0.f;
    o[3] = b3 > 0.f ? sqrtf(b3) : 0.f;
    o[4] = b4 > 0.f ? sqrtf(b4) : 0.f;
  }
}

// ---------------------------------------------------------------------------
// Kernel 3: zero the accumulators (graph-capture-safe init, runs every call)
__global__ void k_init(double* acc) {
  if (threadIdx.x < 2) acc[threadIdx.x] = 0.0;
}

// Kernel 4: merge 4 partial top-5 lists per row -> final 5 NN dists -> sum/sum2
__global__ __launch_bounds__(256) void k_merge(const float* __restrict__ topin,
                                               double* __restrict__ acc) {
  int row = blockIdx.x * 256 + threadIdx.x;
  const float* p = topin + (size_t)row * (CSPLIT * KNN);
  float b0 = INFINITY, b1 = INFINITY, b2 = INFINITY, b3 = INFINITY, b4 = INFINITY;
#pragma unroll
  for (int q = 0; q < CSPLIT * KNN; ++q) {
    float v = p[q];
    INSERT5(b0, b1, b2, b3, b4, v);
  }
  float s = b0 + b1 + b2 + b3 + b4;
  float s2 = b0 * b0 + b1 * b1 + b2 * b2 + b3 * b3 + b4 * b4;
  double ds = (double)s, ds2 = (double)s2;
#pragma unroll
  for (int o = 32; o > 0; o >>= 1) {
    ds += __shfl_down(ds, o);
    ds2 += __shfl_down(ds2, o);
  }
  if ((threadIdx.x & 63) == 0) {
    atomicAdd(&acc[0], ds);
    atomicAdd(&acc[1], ds2);
  }
}

// Kernel 5: final scalar: -std(knn_dist, ddof=1)
__global__ void k_final(const double* __restrict__ acc, float* __restrict__ out) {
  double n = (double)NPTS * (double)KNN;
  double mean = acc[0] / n;
  double var = (acc[1] - n * mean * mean) / (n - 1.0);
  if (var < 0.0) var = 0.0;
  out[0] = -(float)sqrt(var);
}

// ---------------------------------------------------------------------------
extern "C" void kernel_launch(void* const* d_in, const int* in_sizes, int n_in,
                              void* d_out, int out_size, void* d_ws, size_t ws_size,
                              hipStream_t stream) {
  const float* X = (const float*)d_in[0];  // latent[0] = first 8192*512 floats
  char* ws = (char*)d_ws;

  // ws layout: [0, 640KB) partial top-5; [640KB, 672KB) row sq; [672KB, +16) acc
  float* topout = (float*)ws;                                    // 8192*20 f32
  float* sq = (float*)(ws + (size_t)NPTS * CSPLIT * KNN * 4);    // 8192 f32
  double* acc = (double*)(ws + (size_t)NPTS * CSPLIT * KNN * 4 + NPTS * 4);
  float* out = (float*)d_out;

  hipLaunchKernelGGL(k_rowsq, dim3(NPTS / 4), dim3(256), 0, stream, X, sq);
  hipLaunchKernelGGL(k_init, dim3(1), dim3(64), 0, stream, acc);
  hipLaunchKernelGGL(k_knn, dim3((NPTS / RT) * CSPLIT), dim3(256), 0, stream,
                     X, sq, topout);
  hipLaunchKernelGGL(k_merge, dim3(NPTS / 256), dim3(256), 0, stream, topout, acc);
  hipLaunchKernelGGL(k_final, dim3(1), dim3(1), 0, stream, acc, out);
}

// Round 2
// 138.259 us; speedup vs baseline: 8.0206x; 8.0206x over previous
//
#include <hip/hip_runtime.h>
#include <math.h>

#define NPTS 8192
#define DIM 512
#define KNN 5

typedef unsigned short u16;
typedef unsigned int u32;
typedef __attribute__((ext_vector_type(8))) short short8;
typedef __attribute__((ext_vector_type(4))) float f32x4;

// Branch-free sorted insert of v into ascending 5-list (static indices only)
#define INSERT5(t0, t1, t2, t3, t4, v)               \
  do {                                               \
    float _m0 = fmaxf(t0, v);   t0 = fminf(t0, v);   \
    float _m1 = fmaxf(t1, _m0); t1 = fminf(t1, _m0); \
    float _m2 = fmaxf(t2, _m1); t2 = fminf(t2, _m1); \
    t4 = fminf(t4, fmaxf(t3, _m2)); t3 = fminf(t3, _m2); \
  } while (0)

#define GLDS16(g, l)                                                          \
  __builtin_amdgcn_global_load_lds(                                           \
      (const __attribute__((address_space(1))) u32*)(g),                      \
      (__attribute__((address_space(3))) u32*)(l), 16, 0, 0)

__device__ __forceinline__ u16 f2bf(float f) {
  u32 u = __float_as_uint(f);
  u32 r = (u + 0x7fffu + ((u >> 16) & 1u)) >> 16;  // RNE (no NaN in data)
  return (u16)r;
}

// ---------------------------------------------------------------------------
// Kernel 0: fp32 -> bf16 conversion of sample 0 (8192x512)
__global__ __launch_bounds__(256) void k_tobf16(const float* __restrict__ X,
                                                u16* __restrict__ Xb) {
  size_t i = ((size_t)blockIdx.x * 256 + threadIdx.x) * 8;
  const float4* p = (const float4*)(X + i);
  float4 a = p[0], b = p[1];
  u32 o0 = (u32)f2bf(a.x) | ((u32)f2bf(a.y) << 16);
  u32 o1 = (u32)f2bf(a.z) | ((u32)f2bf(a.w) << 16);
  u32 o2 = (u32)f2bf(b.x) | ((u32)f2bf(b.y) << 16);
  u32 o3 = (u32)f2bf(b.z) | ((u32)f2bf(b.w) << 16);
  *(uint4*)(Xb + i) = make_uint4(o0, o1, o2, o3);
}

// ---------------------------------------------------------------------------
// Kernel 1: per-row sum of squares (exact fp32). One wave per row.
__global__ __launch_bounds__(256) void k_rowsq(const float* __restrict__ X,
                                               float* __restrict__ sq) {
  int gt = blockIdx.x * 256 + threadIdx.x;
  int row = gt >> 6;
  int lane = gt & 63;
  const float* r = X + (size_t)row * DIM;
  float4 a = *(const float4*)(r + lane * 8);
  float4 b = *(const float4*)(r + lane * 8 + 4);
  float s = a.x * a.x + a.y * a.y + a.z * a.z + a.w * a.w
          + b.x * b.x + b.y * b.y + b.z * b.z + b.w * b.w;
#pragma unroll
  for (int o = 32; o > 0; o >>= 1) s += __shfl_down(s, o);
  if (lane == 0) sq[row] = s;
}

// ---------------------------------------------------------------------------
// Kernel 2: bf16 MFMA distance tiles + fused per-row (query) top-5.
// Tile 128 (neighbors, M) x 128 (queries, N); 4 waves in 2x2; 4x4 frags/wave.
// D layout (m89): col(query) = lane&15, row(neighbor) = (lane>>4)*4 + reg.
__global__ __launch_bounds__(256, 3) void k_knn_mfma(
    const u16* __restrict__ Xb, const float* __restrict__ sq,
    float* __restrict__ part) {
  __shared__ u16 lds[2][2][128 * 32];        // [buf][A/B][row*32+k] = 32 KB
  __shared__ float mbuf[2][2][4][16][5];     // [wm][wn][nf][q16][5] = 5 KB

  const int tid = threadIdx.x;
  const int lane = tid & 63;
  const int wid = tid >> 6;
  const int wm = wid >> 1;                   // neighbor half
  const int wn = wid & 1;                    // query half
  const int bm = blockIdx.x >> 6;            // neighbor tile (64)
  const int bn = blockIdx.x & 63;            // query tile (64)
  const int n0 = bm * 128;
  const int q0 = bn * 128;

#define STAGE(buf, kk)                                                                   \
  do {                                                                                   \
    GLDS16(Xb + (size_t)(n0 + wid * 32 + 0  + (lane >> 2)) * DIM + (kk) + (lane & 3) * 8,\
           &lds[buf][0][(wid * 32 + 0) * 32]);                                           \
    GLDS16(Xb + (size_t)(n0 + wid * 32 + 16 + (lane >> 2)) * DIM + (kk) + (lane & 3) * 8,\
           &lds[buf][0][(wid * 32 + 16) * 32]);                                          \
    GLDS16(Xb + (size_t)(q0 + wid * 32 + 0  + (lane >> 2)) * DIM + (kk) + (lane & 3) * 8,\
           &lds[buf][1][(wid * 32 + 0) * 32]);                                           \
    GLDS16(Xb + (size_t)(q0 + wid * 32 + 16 + (lane >> 2)) * DIM + (kk) + (lane & 3) * 8,\
           &lds[buf][1][(wid * 32 + 16) * 32]);                                          \
  } while (0)

  f32x4 acc[4][4];
#pragma unroll
  for (int mf = 0; mf < 4; ++mf)
#pragma unroll
    for (int nf = 0; nf < 4; ++nf) acc[mf][nf] = (f32x4){0.f, 0.f, 0.f, 0.f};

  STAGE(0, 0);
  __syncthreads();

#pragma unroll
  for (int step = 0; step < DIM / 32; ++step) {
    const int cur = step & 1;
    if (step < DIM / 32 - 1) STAGE(cur ^ 1, (step + 1) * 32);
    short8 af[4], bf[4];
#pragma unroll
    for (int mf = 0; mf < 4; ++mf)
      af[mf] = *(const short8*)&lds[cur][0][(wm * 64 + mf * 16 + (lane & 15)) * 32 + (lane >> 4) * 8];
#pragma unroll
    for (int nf = 0; nf < 4; ++nf)
      bf[nf] = *(const short8*)&lds[cur][1][(wn * 64 + nf * 16 + (lane & 15)) * 32 + (lane >> 4) * 8];
#pragma unroll
    for (int mf = 0; mf < 4; ++mf)
#pragma unroll
      for (int nf = 0; nf < 4; ++nf)
        acc[mf][nf] = __builtin_amdgcn_mfma_f32_16x16x32_bf16(af[mf], bf[nf], acc[mf][nf], 0, 0, 0);
    __syncthreads();
  }

  // ---- fused epilogue: per-lane top-5 of (sq_n - 2*dot) per owned query ----
  float tl[4][5];
#pragma unroll
  for (int nf = 0; nf < 4; ++nf)
#pragma unroll
    for (int j = 0; j < 5; ++j) tl[nf][j] = 1e30f;

  int qg[4];
#pragma unroll
  for (int nf = 0; nf < 4; ++nf) qg[nf] = q0 + wn * 64 + nf * 16 + (lane & 15);

#pragma unroll
  for (int mf = 0; mf < 4; ++mf) {
#pragma unroll
    for (int reg = 0; reg < 4; ++reg) {
      int ng = n0 + wm * 64 + mf * 16 + (lane >> 4) * 4 + reg;
      float sn = sq[ng];
#pragma unroll
      for (int nf = 0; nf < 4; ++nf) {
        float c = fmaf(-2.f, acc[mf][nf][reg], sn);
        c = (ng == qg[nf]) ? -1e30f : c;   // force exact-0 diagonal
        INSERT5(tl[nf][0], tl[nf][1], tl[nf][2], tl[nf][3], tl[nf][4], c);
      }
    }
  }

  // merge lane quads (lanes l, l^16, l^32, l^48 share a query column)
#pragma unroll
  for (int m = 16; m <= 32; m <<= 1) {
#pragma unroll
    for (int nf = 0; nf < 4; ++nf) {
      float v0 = __shfl_xor(tl[nf][0], m);   // snapshot partner's list first
      float v1 = __shfl_xor(tl[nf][1], m);
      float v2 = __shfl_xor(tl[nf][2], m);
      float v3 = __shfl_xor(tl[nf][3], m);
      float v4 = __shfl_xor(tl[nf][4], m);
      INSERT5(tl[nf][0], tl[nf][1], tl[nf][2], tl[nf][3], tl[nf][4], v0);
      INSERT5(tl[nf][0], tl[nf][1], tl[nf][2], tl[nf][3], tl[nf][4], v1);
      INSERT5(tl[nf][0], tl[nf][1], tl[nf][2], tl[nf][3], tl[nf][4], v2);
      INSERT5(tl[nf][0], tl[nf][1], tl[nf][2], tl[nf][3], tl[nf][4], v3);
      INSERT5(tl[nf][0], tl[nf][1], tl[nf][2], tl[nf][3], tl[nf][4], v4);
    }
  }

  if (lane < 16) {
#pragma unroll
    for (int nf = 0; nf < 4; ++nf)
#pragma unroll
      for (int j = 0; j < 5; ++j) mbuf[wm][wn][nf][lane][j] = tl[nf][j];
  }
  __syncthreads();

  // merge the two neighbor-halves; add sq_q; sqrt; write partial top-5
  if (tid < 128) {
    int wn2 = tid >> 6, nf2 = (tid >> 4) & 3, q = tid & 15;
    float b0 = mbuf[0][wn2][nf2][q][0], b1 = mbuf[0][wn2][nf2][q][1],
          b2 = mbuf[0][wn2][nf2][q][2], b3 = mbuf[0][wn2][nf2][q][3],
          b4 = mbuf[0][wn2][nf2][q][4];
#pragma unroll
    for (int j = 0; j < 5; ++j) {
      float v = mbuf[1][wn2][nf2][q][j];
      INSERT5(b0, b1, b2, b3, b4, v);
    }
    int qgl = q0 + wn2 * 64 + nf2 * 16 + q;
    float sc = sq[qgl];
    float* o = part + ((size_t)bm * NPTS + qgl) * KNN;
    float d0 = b0 + sc, d1 = b1 + sc, d2 = b2 + sc, d3 = b3 + sc, d4 = b4 + sc;
    o[0] = d0 > 0.f ? sqrtf(d0) : 0.f;
    o[1] = d1 > 0.f ? sqrtf(d1) : 0.f;
    o[2] = d2 > 0.f ? sqrtf(d2) : 0.f;
    o[3] = d3 > 0.f ? sqrtf(d3) : 0.f;
    o[4] = d4 > 0.f ? sqrtf(d4) : 0.f;
  }
#undef STAGE
}

// ---------------------------------------------------------------------------
__global__ void k_init(double* acc) {
  if (threadIdx.x < 2) acc[threadIdx.x] = 0.0;
}

// Kernel 3: fold 64 partial top-5 lists per query -> final 5 -> sum/sum2
__global__ __launch_bounds__(256) void k_merge2(const float* __restrict__ part,
                                                double* __restrict__ acc) {
  int q = blockIdx.x * 256 + threadIdx.x;
  float b0 = 1e30f, b1 = 1e30f, b2 = 1e30f, b3 = 1e30f, b4 = 1e30f;
  for (int bm = 0; bm < NPTS / 128; ++bm) {
    const float* p = part + ((size_t)bm * NPTS + q) * KNN;
    float v0 = p[0], v1 = p[1], v2 = p[2], v3 = p[3], v4 = p[4];
    INSERT5(b0, b1, b2, b3, b4, v0);
    INSERT5(b0, b1, b2, b3, b4, v1);
    INSERT5(b0, b1, b2, b3, b4, v2);
    INSERT5(b0, b1, b2, b3, b4, v3);
    INSERT5(b0, b1, b2, b3, b4, v4);
  }
  float s = b0 + b1 + b2 + b3 + b4;
  float s2 = b0 * b0 + b1 * b1 + b2 * b2 + b3 * b3 + b4 * b4;
  double ds = (double)s, ds2 = (double)s2;
#pragma unroll
  for (int o = 32; o > 0; o >>= 1) {
    ds += __shfl_down(ds, o);
    ds2 += __shfl_down(ds2, o);
  }
  if ((threadIdx.x & 63) == 0) {
    atomicAdd(&acc[0], ds);
    atomicAdd(&acc[1], ds2);
  }
}

// Kernel 4: -std(knn_dist, ddof=1)
__global__ void k_final(const double* __restrict__ acc, float* __restrict__ out) {
  double n = (double)NPTS * (double)KNN;
  double mean = acc[0] / n;
  double var = (acc[1] - n * mean * mean) / (n - 1.0);
  if (var < 0.0) var = 0.0;
  out[0] = -(float)sqrt(var);
}

// ---------------------------------------------------------------------------
extern "C" void kernel_launch(void* const* d_in, const int* in_sizes, int n_in,
                              void* d_out, int out_size, void* d_ws, size_t ws_size,
                              hipStream_t stream) {
  const float* X = (const float*)d_in[0];  // latent[0]
  char* ws = (char*)d_ws;

  // ws layout:
  //   part : [64][8192][5] f32        = 10,485,760 B
  //   sq   : [8192] f32               =     32,768 B
  //   acc  : [2] f64                  =         16 B (+pad to 128)
  //   Xb   : [8192*512] bf16          =  8,388,608 B
  const size_t PART_B = (size_t)(NPTS / 128) * NPTS * KNN * 4;
  float* part = (float*)ws;
  float* sq = (float*)(ws + PART_B);
  double* acc = (double*)(ws + PART_B + 32768);
  u16* Xb = (u16*)(ws + PART_B + 32768 + 128);
  float* out = (float*)d_out;

  hipLaunchKernelGGL(k_tobf16, dim3(NPTS * DIM / (8 * 256)), dim3(256), 0, stream, X, Xb);
  hipLaunchKernelGGL(k_rowsq, dim3(NPTS / 4), dim3(256), 0, stream, X, sq);
  hipLaunchKernelGGL(k_init, dim3(1), dim3(64), 0, stream, acc);
  hipLaunchKernelGGL(k_knn_mfma, dim3((NPTS / 128) * (NPTS / 128)), dim3(256), 0,
                     stream, Xb, sq, part);
  hipLaunchKernelGGL(k_merge2, dim3(NPTS / 256), dim3(256), 0, stream, part, acc);
  hipLaunchKernelGGL(k_final, dim3(1), dim3(1), 0, stream, acc, out);
}

// Round 3
// 89.707 us; speedup vs baseline: 12.3617x; 1.5412x over previous
//
#include <hip/hip_runtime.h>
#include <math.h>

#define NPTS 8192
#define DIM 512
#define KNN 5

typedef unsigned short u16;
typedef unsigned int u32;
typedef __attribute__((ext_vector_type(8))) short short8;
typedef __attribute__((ext_vector_type(4))) float f32x4;

// Branch-free sorted insert of v into ascending 5-list (static indices only)
#define INSERT5(t0, t1, t2, t3, t4, v)               \
  do {                                               \
    float _m0 = fmaxf(t0, v);   t0 = fminf(t0, v);   \
    float _m1 = fmaxf(t1, _m0); t1 = fminf(t1, _m0); \
    float _m2 = fmaxf(t2, _m1); t2 = fminf(t2, _m1); \
    t4 = fminf(t4, fmaxf(t3, _m2)); t3 = fminf(t3, _m2); \
  } while (0)

#define GLDS16(g, l)                                                          \
  __builtin_amdgcn_global_load_lds(                                           \
      (const __attribute__((address_space(1))) u32*)(g),                      \
      (__attribute__((address_space(3))) u32*)(l), 16, 0, 0)

__device__ __forceinline__ u16 f2bf(float f) {
  u32 u = __float_as_uint(f);
  u32 r = (u + 0x7fffu + ((u >> 16) & 1u)) >> 16;  // RNE (no NaN in data)
  return (u16)r;
}

// ---------------------------------------------------------------------------
// Kernel 0: fused bf16 convert + per-row sum-of-squares. One wave per row.
__global__ __launch_bounds__(256) void k_prep(const float* __restrict__ X,
                                              u16* __restrict__ Xb,
                                              float* __restrict__ sq) {
  int gt = blockIdx.x * 256 + threadIdx.x;
  int row = gt >> 6;
  int lane = gt & 63;
  const float* r = X + (size_t)row * DIM + lane * 8;
  float4 a = *(const float4*)r;
  float4 b = *(const float4*)(r + 4);
  float s = a.x * a.x + a.y * a.y + a.z * a.z + a.w * a.w
          + b.x * b.x + b.y * b.y + b.z * b.z + b.w * b.w;
  u32 o0 = (u32)f2bf(a.x) | ((u32)f2bf(a.y) << 16);
  u32 o1 = (u32)f2bf(a.z) | ((u32)f2bf(a.w) << 16);
  u32 o2 = (u32)f2bf(b.x) | ((u32)f2bf(b.y) << 16);
  u32 o3 = (u32)f2bf(b.z) | ((u32)f2bf(b.w) << 16);
  *(uint4*)(Xb + (size_t)row * DIM + lane * 8) = make_uint4(o0, o1, o2, o3);
#pragma unroll
  for (int o = 32; o > 0; o >>= 1) s += __shfl_down(s, o);
  if (lane == 0) sq[row] = s;
}

// ---------------------------------------------------------------------------
// Kernel 1: symmetric bf16 MFMA distance tiles, triangular grid (bm >= bn).
// Column epilogue: top-5 per query-col over the tile's 128 rows.
// Row epilogue (bm != bn): top-5 per query-row over the tile's 128 cols,
// via LDS transpose of c' = sq[col] - 2*dot.
// part layout: [query][ntile][5]; every (query, ntile) written exactly once.
__global__ __launch_bounds__(256, 3) void k_knn_sym(
    const u16* __restrict__ Xb, const float* __restrict__ sq,
    float* __restrict__ part) {
  __shared__ __align__(16) char smem[34816];
  u16* ldsu = (u16*)smem;                 // staging: [buf][A/B][row*32+k], 32 KB
  float* mbuf = (float*)smem;             // col-epi merge: [wm][wn][nf][16][5]
  float* lsT = (float*)smem;              // row-epi transpose: [col][68]

  const int tid = threadIdx.x;
  const int lane = tid & 63;
  const int wid = tid >> 6;
  const int wm = wid >> 1;
  const int wn = wid & 1;

  // triangular decode: blockIdx.x -> (bm, bn), bn <= bm
  int t = blockIdx.x;
  int bm = (int)((sqrtf(8.f * t + 1.f) - 1.f) * 0.5f);
  while ((bm + 1) * (bm + 2) / 2 <= t) ++bm;
  while (bm * (bm + 1) / 2 > t) --bm;
  const int bn = t - bm * (bm + 1) / 2;
  const int n0 = bm * 128;
  const int q0 = bn * 128;

#define STG(buf, ab, base, kk)                                                      \
  do {                                                                              \
    GLDS16(Xb + (size_t)((base) + wid * 32 + 0 + (lane >> 2)) * DIM + (kk) +        \
               (lane & 3) * 8,                                                      \
           ldsu + ((buf) * 2 + (ab)) * 4096 + (wid * 32 + 0) * 32);                 \
    GLDS16(Xb + (size_t)((base) + wid * 32 + 16 + (lane >> 2)) * DIM + (kk) +       \
               (lane & 3) * 8,                                                      \
           ldsu + ((buf) * 2 + (ab)) * 4096 + (wid * 32 + 16) * 32);                \
  } while (0)
#define STAGE(buf, kk) do { STG(buf, 0, n0, kk); STG(buf, 1, q0, kk); } while (0)

  f32x4 acc[4][4];
#pragma unroll
  for (int mf = 0; mf < 4; ++mf)
#pragma unroll
    for (int nf = 0; nf < 4; ++nf) acc[mf][nf] = (f32x4){0.f, 0.f, 0.f, 0.f};

  STAGE(0, 0);
  __syncthreads();

#pragma unroll
  for (int step = 0; step < DIM / 32; ++step) {
    const int cur = step & 1;
    if (step < DIM / 32 - 1) STAGE(cur ^ 1, (step + 1) * 32);
    short8 af[4], bf[4];
#pragma unroll
    for (int mf = 0; mf < 4; ++mf)
      af[mf] = *(const short8*)&ldsu[(cur * 2 + 0) * 4096 +
                                     (wm * 64 + mf * 16 + (lane & 15)) * 32 +
                                     (lane >> 4) * 8];
#pragma unroll
    for (int nf = 0; nf < 4; ++nf)
      bf[nf] = *(const short8*)&ldsu[(cur * 2 + 1) * 4096 +
                                     (wn * 64 + nf * 16 + (lane & 15)) * 32 +
                                     (lane >> 4) * 8];
#pragma unroll
    for (int mf = 0; mf < 4; ++mf)
#pragma unroll
      for (int nf = 0; nf < 4; ++nf)
        acc[mf][nf] = __builtin_amdgcn_mfma_f32_16x16x32_bf16(af[mf], bf[nf],
                                                              acc[mf][nf], 0, 0, 0);
    __syncthreads();
  }

  // ---- column epilogue: per query-col top-5 of (sq_row - 2*dot) ----
  int qg[4];
  float sqc[4];
#pragma unroll
  for (int nf = 0; nf < 4; ++nf) {
    qg[nf] = q0 + wn * 64 + nf * 16 + (lane & 15);
    sqc[nf] = sq[qg[nf]];
  }

  float tl[4][5];
#pragma unroll
  for (int nf = 0; nf < 4; ++nf)
#pragma unroll
    for (int j = 0; j < 5; ++j) tl[nf][j] = 1e30f;

#pragma unroll
  for (int mf = 0; mf < 4; ++mf) {
#pragma unroll
    for (int reg = 0; reg < 4; ++reg) {
      int ng = n0 + wm * 64 + mf * 16 + (lane >> 4) * 4 + reg;
      float sn = sq[ng];
#pragma unroll
      for (int nf = 0; nf < 4; ++nf) {
        float c = fmaf(-2.f, acc[mf][nf][reg], sn);
        c = (ng == qg[nf]) ? -1e30f : c;   // exact-0 diagonal (diag tiles only)
        INSERT5(tl[nf][0], tl[nf][1], tl[nf][2], tl[nf][3], tl[nf][4], c);
      }
    }
  }

#pragma unroll
  for (int m = 16; m <= 32; m <<= 1) {
#pragma unroll
    for (int nf = 0; nf < 4; ++nf) {
      float v0 = __shfl_xor(tl[nf][0], m);
      float v1 = __shfl_xor(tl[nf][1], m);
      float v2 = __shfl_xor(tl[nf][2], m);
      float v3 = __shfl_xor(tl[nf][3], m);
      float v4 = __shfl_xor(tl[nf][4], m);
      INSERT5(tl[nf][0], tl[nf][1], tl[nf][2], tl[nf][3], tl[nf][4], v0);
      INSERT5(tl[nf][0], tl[nf][1], tl[nf][2], tl[nf][3], tl[nf][4], v1);
      INSERT5(tl[nf][0], tl[nf][1], tl[nf][2], tl[nf][3], tl[nf][4], v2);
      INSERT5(tl[nf][0], tl[nf][1], tl[nf][2], tl[nf][3], tl[nf][4], v3);
      INSERT5(tl[nf][0], tl[nf][1], tl[nf][2], tl[nf][3], tl[nf][4], v4);
    }
  }

  if (lane < 16) {
#pragma unroll
    for (int nf = 0; nf < 4; ++nf)
#pragma unroll
      for (int j = 0; j < 5; ++j)
        mbuf[(((wm * 2 + wn) * 4 + nf) * 16 + lane) * 5 + j] = tl[nf][j];
  }
  __syncthreads();

  if (tid < 128) {
    int wn2 = tid >> 6, nf2 = (tid >> 4) & 3, q = tid & 15;
    const float* m0 = &mbuf[(((0 * 2 + wn2) * 4 + nf2) * 16 + q) * 5];
    const float* m1 = &mbuf[(((1 * 2 + wn2) * 4 + nf2) * 16 + q) * 5];
    float b0 = m0[0], b1 = m0[1], b2 = m0[2], b3 = m0[3], b4 = m0[4];
#pragma unroll
    for (int j = 0; j < 5; ++j) {
      float v = m1[j];
      INSERT5(b0, b1, b2, b3, b4, v);
    }
    int qgl = q0 + wn2 * 64 + nf2 * 16 + q;
    float sc = sq[qgl];
    float* o = part + ((size_t)qgl * (NPTS / 128) + bm) * KNN;
    float d0 = b0 + sc, d1 = b1 + sc, d2 = b2 + sc, d3 = b3 + sc, d4 = b4 + sc;
    o[0] = d0 > 0.f ? sqrtf(d0) : 0.f;
    o[1] = d1 > 0.f ? sqrtf(d1) : 0.f;
    o[2] = d2 > 0.f ? sqrtf(d2) : 0.f;
    o[3] = d3 > 0.f ? sqrtf(d3) : 0.f;
    o[4] = d4 > 0.f ? sqrtf(d4) : 0.f;
  }

  // ---- row epilogue (off-diagonal blocks): queries = this tile's rows ----
  if (bm != bn) {
#pragma unroll
    for (int p = 0; p < 2; ++p) {          // row chunks: mf = 2p, 2p+1
      __syncthreads();                     // protect mbuf / previous lsT readers
#pragma unroll
      for (int mh = 0; mh < 2; ++mh) {
        int mf = 2 * p + mh;
        int rl = wm * 32 + mh * 16 + (lane >> 4) * 4;
#pragma unroll
        for (int nf = 0; nf < 4; ++nf) {
          int cl = wn * 64 + nf * 16 + (lane & 15);
          f32x4 cp;
#pragma unroll
          for (int reg = 0; reg < 4; ++reg)
            cp[reg] = fmaf(-2.f, acc[mf][nf][reg], sqc[nf]);
          *(f32x4*)&lsT[cl * 68 + rl] = cp;   // 16B-aligned (rl%4==0, 68%4==0)
        }
      }
      __syncthreads();
      int r = tid >> 2, qq = tid & 3;        // 4 threads per row, 32 cols each
      float b0 = 1e30f, b1 = 1e30f, b2 = 1e30f, b3 = 1e30f, b4 = 1e30f;
#pragma unroll
      for (int i = 0; i < 32; ++i) {
        float v = lsT[(qq * 32 + i) * 68 + r];
        INSERT5(b0, b1, b2, b3, b4, v);
      }
#pragma unroll
      for (int m = 1; m <= 2; m <<= 1) {
        float v0 = __shfl_xor(b0, m);
        float v1 = __shfl_xor(b1, m);
        float v2 = __shfl_xor(b2, m);
        float v3 = __shfl_xor(b3, m);
        float v4 = __shfl_xor(b4, m);
        INSERT5(b0, b1, b2, b3, b4, v0);
        INSERT5(b0, b1, b2, b3, b4, v1);
        INSERT5(b0, b1, b2, b3, b4, v2);
        INSERT5(b0, b1, b2, b3, b4, v3);
        INSERT5(b0, b1, b2, b3, b4, v4);
      }
      if ((tid & 3) == 0) {
        int ng = n0 + (r >> 5) * 64 + p * 32 + (r & 31);
        float sn = sq[ng];
        float* o = part + ((size_t)ng * (NPTS / 128) + bn) * KNN;
        float d0 = b0 + sn, d1 = b1 + sn, d2 = b2 + sn, d3 = b3 + sn, d4 = b4 + sn;
        o[0] = d0 > 0.f ? sqrtf(d0) : 0.f;
        o[1] = d1 > 0.f ? sqrtf(d1) : 0.f;
        o[2] = d2 > 0.f ? sqrtf(d2) : 0.f;
        o[3] = d3 > 0.f ? sqrtf(d3) : 0.f;
        o[4] = d4 > 0.f ? sqrtf(d4) : 0.f;
      }
    }
  }
#undef STAGE
#undef STG
}

// ---------------------------------------------------------------------------
// Kernel 2: fold 64 partial top-5 per query -> per-block (sum, sum2) partials.
// part layout [query][64][5]: each query's candidates are 320 contiguous f32.
__global__ __launch_bounds__(256) void k_merge(const float* __restrict__ part,
                                               double* __restrict__ pacc) {
  __shared__ double red[8];
  int tid = threadIdx.x;
  int q = blockIdx.x * 64 + (tid >> 2);
  int quarter = tid & 3;
  const float4* p =
      (const float4*)(part + ((size_t)q * (NPTS / 128) + quarter * 16) * KNN);
  float b0 = 1e30f, b1 = 1e30f, b2 = 1e30f, b3 = 1e30f, b4 = 1e30f;
#pragma unroll
  for (int i = 0; i < 20; ++i) {
    float4 v = p[i];
    INSERT5(b0, b1, b2, b3, b4, v.x);
    INSERT5(b0, b1, b2, b3, b4, v.y);
    INSERT5(b0, b1, b2, b3, b4, v.z);
    INSERT5(b0, b1, b2, b3, b4, v.w);
  }
#pragma unroll
  for (int m = 1; m <= 2; m <<= 1) {
    float v0 = __shfl_xor(b0, m);
    float v1 = __shfl_xor(b1, m);
    float v2 = __shfl_xor(b2, m);
    float v3 = __shfl_xor(b3, m);
    float v4 = __shfl_xor(b4, m);
    INSERT5(b0, b1, b2, b3, b4, v0);
    INSERT5(b0, b1, b2, b3, b4, v1);
    INSERT5(b0, b1, b2, b3, b4, v2);
    INSERT5(b0, b1, b2, b3, b4, v3);
    INSERT5(b0, b1, b2, b3, b4, v4);
  }
  double ds = 0.0, ds2 = 0.0;
  if ((tid & 3) == 0) {
    float s = b0 + b1 + b2 + b3 + b4;
    float s2 = b0 * b0 + b1 * b1 + b2 * b2 + b3 * b3 + b4 * b4;
    ds = (double)s;
    ds2 = (double)s2;
  }
#pragma unroll
  for (int o = 32; o > 0; o >>= 1) {
    ds += __shfl_down(ds, o);
    ds2 += __shfl_down(ds2, o);
  }
  if ((tid & 63) == 0) {
    red[2 * (tid >> 6)] = ds;
    red[2 * (tid >> 6) + 1] = ds2;
  }
  __syncthreads();
  if (tid == 0) {
    double s = red[0] + red[2] + red[4] + red[6];
    double s2 = red[1] + red[3] + red[5] + red[7];
    pacc[2 * blockIdx.x] = s;
    pacc[2 * blockIdx.x + 1] = s2;
  }
}

// Kernel 3: fold 128 block partials -> -std(knn_dist, ddof=1)
__global__ void k_final(const double* __restrict__ pacc, float* __restrict__ out) {
  int lane = threadIdx.x;
  double s = pacc[2 * lane] + pacc[2 * (lane + 64)];
  double s2 = pacc[2 * lane + 1] + pacc[2 * (lane + 64) + 1];
#pragma unroll
  for (int o = 32; o > 0; o >>= 1) {
    s += __shfl_down(s, o);
    s2 += __shfl_down(s2, o);
  }
  if (lane == 0) {
    double n = (double)NPTS * (double)KNN;
    double mean = s / n;
    double var = (s2 - n * mean * mean) / (n - 1.0);
    if (var < 0.0) var = 0.0;
    out[0] = -(float)sqrt(var);
  }
}

// ---------------------------------------------------------------------------
extern "C" void kernel_launch(void* const* d_in, const int* in_sizes, int n_in,
                              void* d_out, int out_size, void* d_ws, size_t ws_size,
                              hipStream_t stream) {
  const float* X = (const float*)d_in[0];  // latent[0]
  char* ws = (char*)d_ws;

  // ws: part [8192][64][5] f32 (10.5 MB) | sq [8192] f32 | pacc [256] f64 | Xb bf16 (8 MB)
  const size_t PART_B = (size_t)NPTS * (NPTS / 128) * KNN * 4;
  float* part = (float*)ws;
  float* sq = (float*)(ws + PART_B);
  double* pacc = (double*)(ws + PART_B + 32768);
  u16* Xb = (u16*)(ws + PART_B + 32768 + 2048);
  float* out = (float*)d_out;

  const int NT = NPTS / 128;                       // 64 tiles per dim
  hipLaunchKernelGGL(k_prep, dim3(NPTS / 4), dim3(256), 0, stream, X, Xb, sq);
  hipLaunchKernelGGL(k_knn_sym, dim3(NT * (NT + 1) / 2), dim3(256), 0, stream,
                     Xb, sq, part);
  hipLaunchKernelGGL(k_merge, dim3(NPTS / 64), dim3(256), 0, stream, part, pacc);
  hipLaunchKernelGGL(k_final, dim3(1), dim3(64), 0, stream, pacc, out);
}